// Round 8
// baseline (832.229 us; speedup 1.0000x reference)
//
#include <hip/hip_runtime.h>

typedef unsigned short u16;
typedef unsigned int   u32;
typedef __attribute__((ext_vector_type(4))) u16   u16x4;
typedef __attribute__((ext_vector_type(8))) u16   u16x8;
typedef __attribute__((ext_vector_type(8))) __bf16 bf16x8;
typedef __attribute__((ext_vector_type(4))) float f32x4;

#define DEV static __device__ __forceinline__

constexpr int DIM = 512, NHEAD = 8, DHEAD = 64, DFFN = 2048, NLAY = 6, SEQ = 512, BATCH = 8;
constexpr int MROWS = BATCH * SEQ;            // 4096 token rows
constexpr long HD = (long)SEQ * DHEAD;        // 32768 per-head q/k/v block
constexpr long SQ = (long)DIM * DIM;          // 262144

DEV float bf2f(u16 u) { union { u32 i; float f; } x; x.i = (u32)u << 16; return x.f; }
DEV u16 f2bf(float f) { union { float f; u32 i; } x; x.f = f; u32 r = x.i + 0x7fffu + ((x.i >> 16) & 1u); return (u16)(r >> 16); }

DEV void gl_lds16(const u16* g, u16* l) {
    __builtin_amdgcn_global_load_lds((const __attribute__((address_space(1))) u32*)(const void*)g,
                                     (__attribute__((address_space(3))) u32*)(void*)l, 16, 0, 0);
}

// counted vmcnt wait + scheduler fence (rule #18)
template <int N> DEV void waitcnt_vm() {
    if constexpr (N == 0)      asm volatile("s_waitcnt vmcnt(0)" ::: "memory");
    else if constexpr (N == 2) asm volatile("s_waitcnt vmcnt(2)" ::: "memory");
    else if constexpr (N == 4) asm volatile("s_waitcnt vmcnt(4)" ::: "memory");
    else if constexpr (N == 8) asm volatile("s_waitcnt vmcnt(8)" ::: "memory");
    else static_assert(N == 0, "unsupported vmcnt");
    __builtin_amdgcn_sched_barrier(0);
}

// ---------------------------------------------------------------------------
// Merged transpose for the 8 square (512x512 per layer) weights.
// ---------------------------------------------------------------------------
struct TP { const float* in[8]; u16* out[8]; long ls[8]; };

__global__ __launch_bounds__(256) void transpose8(TP p)
{
    __shared__ u16 t[32][33];
    int z = blockIdx.z, which = z / NLAY, l = z % NLAY;
    const float* in = p.in[which] + (long)l * SQ;
    u16* out = p.out[which] + (long)l * p.ls[which];
    int k0 = blockIdx.y * 32, n0 = blockIdx.x * 32;
    int tx = threadIdx.x & 31, ty = threadIdx.x >> 5;
    #pragma unroll
    for (int i = ty; i < 32; i += 8) t[i][tx] = f2bf(in[(long)(k0 + i) * 512 + n0 + tx]);
    __syncthreads();
    #pragma unroll
    for (int i = ty; i < 32; i += 8) out[(long)(n0 + i) * 512 + k0 + tx] = t[tx][i];
}

// generic transpose (for W1/W2): out[z*outLS + n*K + k] = bf16(in[z*K*N + k*N + n])
__global__ __launch_bounds__(256) void transpose_w(const float* __restrict__ in, u16* __restrict__ out,
                                                   int K, int N, long outLS)
{
    __shared__ u16 t[32][33];
    long bi = (long)blockIdx.z * K * N, bo = (long)blockIdx.z * outLS;
    int k0 = blockIdx.y * 32, n0 = blockIdx.x * 32;
    int tx = threadIdx.x & 31, ty = threadIdx.x >> 5;
    #pragma unroll
    for (int i = ty; i < 32; i += 8) t[i][tx] = f2bf(in[bi + (long)(k0 + i) * N + n0 + tx]);
    __syncthreads();
    #pragma unroll
    for (int i = ty; i < 32; i += 8) out[bo + (long)(n0 + i) * K + k0 + tx] = t[tx][i];
}

// concat per-layer bias vectors (each NLAY x 512) into [NLAY][nsrc*512]
__global__ __launch_bounds__(256) void concat_bias(const float* __restrict__ a, const float* __restrict__ b,
                                                   const float* __restrict__ c, float* __restrict__ out, int nsrc)
{
    int i = blockIdx.x * 256 + threadIdx.x;
    int col = i & 511, j = (i >> 9) % nsrc, l = i / (nsrc * 512);
    const float* s = (j == 0) ? a : (j == 1) ? b : c;
    out[i] = s[l * 512 + col];
}

__global__ __launch_bounds__(256) void conv_f32_bf16(const float* __restrict__ in, u16* __restrict__ out)
{
    long i = ((long)blockIdx.x * 256 + threadIdx.x) * 4;
    float4 v = *(const float4*)(in + i);
    u16x4 o; o.x = f2bf(v.x); o.y = f2bf(v.y); o.z = f2bf(v.z); o.w = f2bf(v.w);
    *(u16x4*)(out + i) = o;
}

// ---------------------------------------------------------------------------
// Embedding * sqrt(D) + sinusoidal positional encoding -> xb (bf16 residual)
// ---------------------------------------------------------------------------
__global__ __launch_bounds__(256) void embed_pe(const int* __restrict__ targets, const float* __restrict__ emb,
                                                u16* __restrict__ xb)
{
    int t4 = (blockIdx.x * 256 + threadIdx.x) * 4;
    int d = t4 & (DIM - 1);
    int s = (t4 >> 9) & (SEQ - 1);
    int b = t4 >> 18;
    int tok = targets[s * BATCH + b];
    float4 e = *(const float4*)(emb + (long)tok * DIM + d);
    u16x4 ob;
    const float ef[4] = { e.x, e.y, e.z, e.w };
    #pragma unroll
    for (int j = 0; j < 4; ++j) {
        int dd = d + j;
        float div = expf((float)(dd & ~1) * -0.017988946039016f);  // -ln(10000)/512
        float ang = (float)s * div;
        float pe = (dd & 1) ? cosf(ang) : sinf(ang);
        ob[j] = f2bf(ef[j] * 22.627416997969522f + pe);            // sqrt(512)
    }
    *(u16x4*)(xb + ((long)b * SEQ + s) * DIM + d) = ob;
}

// scatter helpers: (B*S, D)-indexed value -> head-split layouts
DEV void scat_sd(u16* dst, int mm, int col, float v) {   // (B,NH,S,DH)
    dst[(long)((mm >> 9) * NHEAD + (col >> 6)) * HD + (long)(mm & 511) * DHEAD + (col & 63)] = f2bf(v);
}
DEV void scat_ds(u16* dst, int mm, int col, float v) {   // (B,NH,DH,S)
    dst[(long)((mm >> 9) * NHEAD + (col >> 6)) * HD + (long)(col & 63) * SEQ + (mm & 511)] = f2bf(v);
}

// ---------------------------------------------------------------------------
// GEMM: C = A @ Bt^T + bias.  BM x BN tile, BK=32, 4 waves (wave BM/2 x BN/2).
// QUAD-buffered LDS, prefetch depth 3, counted vmcnt + raw s_barrier (T4):
// never drain vmcnt to 0 in the main loop; steady wait = 2*CPW (stages t+2,
// t+3 in flight), epilogue CPW -> 0. Buffer distance 4 > depth 3: no overlap.
// Chunk = 16 rows x 32 elems (64B rows). Both-sides swizzle for 64B rows:
//   stage: lane source slot = (l&3) ^ ((l>>3)&3)   (row-in-chunk = l>>2)
//   read : byte ^= ((row>>1)&3) << 4
// -> 8 distinct 16B slots per 16-lane group = conflict-free ds_read_b128.
// A pointer per block: n0 < aSplit ? A0 : A1 (fused cross Q|K|V).
// 1D grid + bijective XCD-chunk swizzle (grid % 8 == 0).
// EPI: 0=bf16 plain, 1=bf16+relu, 4=QKV head-split scatter
// ---------------------------------------------------------------------------
template <int BM, int BN, int EPI>
__global__ __launch_bounds__(256) void gemm_t(const u16* __restrict__ A0, const u16* __restrict__ A1,
                                              const u16* __restrict__ Bt,
                                              void* __restrict__ C0, void* __restrict__ C1, void* __restrict__ C2,
                                              const float* __restrict__ bias, int K, int ldc, int gx, int aSplit)
{
    constexpr int NCHA = BM / 16;         // 16-row A chunks
    constexpr int NCH  = (BM + BN) / 16;  // total chunks per buffer
    constexpr int CPW  = NCH / 4;         // chunks per wave (gl_lds per wave per stage)
    constexpr int MI   = BM / 32;         // M frags per wave
    constexpr int NI   = BN / 32;         // N frags per wave
    __shared__ __align__(16) u16 lds[4][NCH * 512];

    const int tid = threadIdx.x, lane = tid & 63, wid = tid >> 6;
    const int nwg = gridDim.x, bid = blockIdx.x;
    const int wg = (bid & 7) * (nwg >> 3) + (bid >> 3);     // XCD-chunk swizzle
    const int m0 = (wg / gx) * BM, n0 = (wg % gx) * BN;
    const u16* A = (n0 < aSplit) ? A0 : A1;
    const int wr = (wid >> 1) * (BM / 2), wc = (wid & 1) * (BN / 2);
    const int fr = lane & 15, fq = lane >> 4;
    const int srow = lane >> 2;                              // 0..15 row in chunk
    const int scol = ((lane & 3) ^ ((lane >> 3) & 3)) * 8;   // pre-swizzled source col

    f32x4 acc[MI][NI] = {};

    auto stage = [&](int buf, int k0) {
        #pragma unroll
        for (int c = wid; c < NCH; c += 4) {
            if (c < NCHA) gl_lds16(A  + (long)(m0 + c * 16 + srow) * K + k0 + scol, &lds[buf][c * 512]);
            else          gl_lds16(Bt + (long)(n0 + (c - NCHA) * 16 + srow) * K + k0 + scol, &lds[buf][c * 512]);
        }
    };

    const int nt = K >> 5;                 // BK=32; nt >= 16 for all our shapes
    stage(0, 0); stage(1, 32); stage(2, 64);
    waitcnt_vm<2 * CPW>();                 // stage0 landed (t+1,t+2 in flight)
    __builtin_amdgcn_s_barrier();
    __builtin_amdgcn_sched_barrier(0);

    for (int t = 0; t < nt; ++t) {
        if (t + 3 < nt) stage((t + 3) & 3, (t + 3) << 5);
        const char* lb = (const char*)&lds[t & 3][0];
        bf16x8 a[MI], b[NI];
        #pragma unroll
        for (int mi = 0; mi < MI; ++mi) {
            int row = wr + mi * 16 + fr;
            a[mi] = *(const bf16x8*)(lb + row * 64 + ((fq * 16) ^ (((row >> 1) & 3) << 4)));
        }
        #pragma unroll
        for (int ni = 0; ni < NI; ++ni) {
            int row = BM + wc + ni * 16 + fr;
            b[ni] = *(const bf16x8*)(lb + row * 64 + ((fq * 16) ^ (((row >> 1) & 3) << 4)));
        }
        #pragma unroll
        for (int mi = 0; mi < MI; ++mi)
            #pragma unroll
            for (int ni = 0; ni < NI; ++ni)
                acc[mi][ni] = __builtin_amdgcn_mfma_f32_16x16x32_bf16(a[mi], b[ni], acc[mi][ni], 0, 0, 0);
        if (t + 1 < nt) {
            if (t + 3 < nt)       waitcnt_vm<2 * CPW>();   // allow t+2, t+3 in flight
            else if (t + 3 == nt) waitcnt_vm<CPW>();       // allow t+2 (== nt-1)
            else                  waitcnt_vm<0>();         // last prefetched stage
            __builtin_amdgcn_s_barrier();
            __builtin_amdgcn_sched_barrier(0);
        }
    }

    #pragma unroll
    for (int mi = 0; mi < MI; ++mi)
    #pragma unroll
    for (int ni = 0; ni < NI; ++ni)
    #pragma unroll
    for (int rr = 0; rr < 4; ++rr) {
        int mm = m0 + wr + mi * 16 + fq * 4 + rr;
        int nn = n0 + wc + ni * 16 + fr;
        float v = acc[mi][ni][rr] + bias[nn];
        if (EPI == 0) {
            ((u16*)C0)[(long)mm * ldc + nn] = f2bf(v);
        } else if (EPI == 1) {
            ((u16*)C0)[(long)mm * ldc + nn] = f2bf(fmaxf(v, 0.f));
        } else {            // QKV head-split
            int which = nn >> 9, col = nn & 511;
            if (which == 0)      scat_sd((u16*)C0, mm, col, v);
            else if (which == 1) scat_sd((u16*)C1, mm, col, v);
            else                 scat_ds((u16*)C2, mm, col, v);
        }
    }
}

// ---------------------------------------------------------------------------
// Flash attention: block = (head = bid & 63, qt = bid >> 6) so all 8 q-tiles
// of a head land on ONE XCD. 4 waves x 16 q-rows. KV tiles of 128, double-
// buffered LDS, both-sides XOR swizzle on K and V. Online softmax in C-layout
// registers; P via swizzled per-wave LDS slab. setprio around MFMA.
// ---------------------------------------------------------------------------
template <bool CAUSAL>
__global__ __launch_bounds__(256) void flash_attn(const u16* __restrict__ qh, const u16* __restrict__ kh,
                                                  const u16* __restrict__ vT, u16* __restrict__ ctx)
{
    constexpr int KVB = 128;
    __shared__ __align__(16) u16 Kl[2][KVB * 64];    // kv x dh, swizzled
    __shared__ __align__(16) u16 Vl[2][64 * KVB];    // dh x kv, swizzled
    __shared__ __align__(16) u16 Pl[4][16 * KVB];    // per-wave P, swizzled
    const int lane = threadIdx.x & 63, wid = threadIdx.x >> 6;
    const int head = blockIdx.x & 63, qt = blockIdx.x >> 6;   // head-major: XCD = head%8
    const int q0 = qt * 64;
    const long hb = (long)head * HD;
    const int fr = lane & 15, fq = lane >> 4;
    const int swz = (fr & 7) << 4;

    bf16x8 qf[2];
    #pragma unroll
    for (int kf = 0; kf < 2; ++kf)
        qf[kf] = *(const bf16x8*)(qh + hb + (long)(q0 + wid * 16 + fr) * 64 + kf * 32 + fq * 8);

    const int nt = CAUSAL ? (q0 >> 7) + 1 : SEQ / KVB;

    auto stage = [&](int buf, int t) {
        const long kv0 = (long)t * KVB;
        const int kr = lane >> 3;                        // K: 8 rows/chunk
        const int kcol = ((lane & 7) ^ kr) * 8;
        for (int c = wid; c < 16; c += 4)
            gl_lds16(kh + hb + (kv0 + c * 8 + kr) * 64 + kcol, &Kl[buf][c * 512]);
        const int vr = lane >> 4;                        // V^T: 4 rows/chunk
        for (int c = wid; c < 16; c += 4) {
            int row = c * 4 + vr;
            int vcol = ((lane & 15) ^ (row & 7)) * 8;
            gl_lds16(vT + hb + (long)row * SEQ + kv0 + vcol, &Vl[buf][c * 512]);
        }
    };

    float m[4], l[4];
    #pragma unroll
    for (int r = 0; r < 4; ++r) { m[r] = -3.0e38f; l[r] = 0.f; }
    f32x4 ao[4] = {};

    stage(0, 0);
    __syncthreads();
    int cur = 0;
    for (int t = 0; t < nt; ++t) {
        if (t + 1 < nt) stage(cur ^ 1, t + 1);
        f32x4 as[8] = {};
        const char* kb = (const char*)&Kl[cur][0];
        __builtin_amdgcn_s_setprio(1);
        #pragma unroll
        for (int nf = 0; nf < 8; ++nf)
            #pragma unroll
            for (int kf = 0; kf < 2; ++kf) {
                bf16x8 kfr = *(const bf16x8*)(kb + (nf * 16 + fr) * 128 + ((kf * 64 + fq * 16) ^ swz));
                as[nf] = __builtin_amdgcn_mfma_f32_16x16x32_bf16(qf[kf], kfr, as[nf], 0, 0, 0);
            }
        __builtin_amdgcn_s_setprio(0);
        const int kv0 = t * KVB;
        const int qrow = q0 + wid * 16 + fq * 4;
        #pragma unroll
        for (int nf = 0; nf < 8; ++nf)
            #pragma unroll
            for (int rr = 0; rr < 4; ++rr) {
                float s = as[nf][rr] * 0.125f;
                if (CAUSAL && (kv0 + nf * 16 + fr > qrow + rr)) s = -3.0e38f;
                as[nf][rr] = s;
            }
        float p_scale[4];
        #pragma unroll
        for (int rr = 0; rr < 4; ++rr) {
            float mx = as[0][rr];
            #pragma unroll
            for (int nf = 1; nf < 8; ++nf) mx = fmaxf(mx, as[nf][rr]);
            #pragma unroll
            for (int o = 1; o < 16; o <<= 1) mx = fmaxf(mx, __shfl_xor(mx, o, 64));
            float mnew = fmaxf(m[rr], mx);
            p_scale[rr] = __expf(m[rr] - mnew);
            m[rr] = mnew;
        }
        float rsum[4] = {0.f, 0.f, 0.f, 0.f};
        u16* pw = &Pl[wid][0];
        #pragma unroll
        for (int nf = 0; nf < 8; ++nf)
            #pragma unroll
            for (int rr = 0; rr < 4; ++rr) {
                float p = __expf(as[nf][rr] - m[rr]);
                rsum[rr] += p;
                int row = fq * 4 + rr;
                int byte = (row * 256 + (nf * 16 + fr) * 2) ^ ((row & 7) << 4);
                *(u16*)((char*)pw + byte) = f2bf(p);
            }
        #pragma unroll
        for (int rr = 0; rr < 4; ++rr) {
            #pragma unroll
            for (int o = 1; o < 16; o <<= 1) rsum[rr] += __shfl_xor(rsum[rr], o, 64);
            l[rr] = l[rr] * p_scale[rr] + rsum[rr];
        }
        #pragma unroll
        for (int nf = 0; nf < 4; ++nf)
            #pragma unroll
            for (int rr = 0; rr < 4; ++rr) ao[nf][rr] *= p_scale[rr];
        const char* vb = (const char*)&Vl[cur][0];
        __builtin_amdgcn_s_setprio(1);
        #pragma unroll
        for (int kf = 0; kf < 4; ++kf) {
            int pbyte = (fr * 256 + kf * 64 + fq * 16) ^ swz;
            bf16x8 pa = *(const bf16x8*)((const char*)pw + pbyte);
            #pragma unroll
            for (int nf = 0; nf < 4; ++nf) {
                bf16x8 vf = *(const bf16x8*)(vb + (nf * 16 + fr) * 256 + ((kf * 64 + fq * 16) ^ swz));
                ao[nf] = __builtin_amdgcn_mfma_f32_16x16x32_bf16(pa, vf, ao[nf], 0, 0, 0);
            }
        }
        __builtin_amdgcn_s_setprio(0);
        __syncthreads();
        cur ^= 1;
    }
    const int b = head >> 3, h = head & 7;
    #pragma unroll
    for (int nf = 0; nf < 4; ++nf)
        #pragma unroll
        for (int rr = 0; rr < 4; ++rr) {
            int qq = q0 + wid * 16 + fq * 4 + rr;
            ctx[((long)(b * SEQ + qq)) * DIM + h * 64 + nf * 16 + fr] = f2bf(ao[nf][rr] / l[rr]);
        }
}

// ---------------------------------------------------------------------------
// xb = LayerNorm(xb + y) * g + be, in place (bf16 residual stream).
// If xf != nullptr, also write f32 copy (final layer output).
// ---------------------------------------------------------------------------
__global__ __launch_bounds__(256) void add_ln(u16* xb, const u16* __restrict__ y,
                                              const float* __restrict__ g, const float* __restrict__ be,
                                              float* __restrict__ xf)
{
    int row = blockIdx.x * 4 + (threadIdx.x >> 6);
    int lane = threadIdx.x & 63;
    long off = (long)row * DIM + lane * 8;
    u16x8 xv = *(const u16x8*)(xb + off);
    u16x8 yv = *(const u16x8*)(y + off);
    float v[8];
    #pragma unroll
    for (int j = 0; j < 8; ++j) v[j] = bf2f(xv[j]) + bf2f(yv[j]);
    float sum = 0.f;
    #pragma unroll
    for (int j = 0; j < 8; ++j) sum += v[j];
    #pragma unroll
    for (int o = 32; o; o >>= 1) sum += __shfl_xor(sum, o, 64);
    float mean = sum * (1.0f / DIM);
    float vs = 0.f;
    #pragma unroll
    for (int j = 0; j < 8; ++j) { float d = v[j] - mean; vs += d * d; }
    #pragma unroll
    for (int o = 32; o; o >>= 1) vs += __shfl_xor(vs, o, 64);
    float rstd = rsqrtf(vs * (1.0f / DIM) + 1e-5f);
    float outv[8]; u16x8 ob;
    #pragma unroll
    for (int j = 0; j < 8; ++j) {
        int col = lane * 8 + j;
        float r = (v[j] - mean) * rstd * g[col] + be[col];
        outv[j] = r; ob[j] = f2bf(r);
    }
    *(u16x8*)(xb + off) = ob;
    if (xf) {
        *(float4*)(xf + off)     = *(const float4*)&outv[0];
        *(float4*)(xf + off + 4) = *(const float4*)&outv[4];
    }
}

// ---------------------------------------------------------------------------
extern "C" void kernel_launch(void* const* d_in, const int* in_sizes, int n_in,
                              void* d_out, int out_size, void* d_ws, size_t ws_size,
                              hipStream_t stream)
{
    const int*   targets = (const int*)  d_in[0];
    const float* memory  = (const float*)d_in[1];
    // d_in[2]=trg_mask (causal, analytic), d_in[3]=memory_mask (all false) -> unread
    const float* emb     = (const float*)d_in[4];
    const float* Wg[8]; for (int i = 0; i < 8; ++i) Wg[i] = (const float*)d_in[5 + i];
    const float* bg[8]; for (int i = 0; i < 8; ++i) bg[i] = (const float*)d_in[13 + i];
    const float* W1  = (const float*)d_in[21];
    const float* b1  = (const float*)d_in[22];
    const float* W2  = (const float*)d_in[23];
    const float* b2  = (const float*)d_in[24];
    const float* g1  = (const float*)d_in[25];
    const float* g2  = (const float*)d_in[26];
    const float* g3  = (const float*)d_in[27];
    const float* be1 = (const float*)d_in[28];
    const float* be2 = (const float*)d_in[29];
    const float* be3 = (const float*)d_in[30];

    char* w = (char*)d_ws;
    auto take = [&](size_t n) -> char* { char* p = w; w += (n + 255) & ~(size_t)255; return p; };
    u16*   wqkvT = (u16*)take((size_t)NLAY * 3 * SQ * 2);   // self  [L][1536][512]
    u16*   wcatT = (u16*)take((size_t)NLAY * 3 * SQ * 2);   // cross [L][1536][512]
    u16*   woT   = (u16*)take((size_t)NLAY * SQ * 2);
    u16*   wocT  = (u16*)take((size_t)NLAY * SQ * 2);
    u16*   w1T   = (u16*)take((size_t)NLAY * DIM * DFFN * 2);
    u16*   w2T   = (u16*)take((size_t)NLAY * DIM * DFFN * 2);
    float* bqkv  = (float*)take((size_t)NLAY * 3 * DIM * 4);
    float* bqkvc = (float*)take((size_t)NLAY * 3 * DIM * 4);
    u16*   xb    = (u16*)  take((size_t)MROWS * DIM * 2);   // bf16 residual stream
    u16*   y     = (u16*)  take((size_t)MROWS * DIM * 2);
    u16*   memb  = (u16*)  take((size_t)MROWS * DIM * 2);
    u16*   qh    = (u16*)  take((size_t)MROWS * DIM * 2);
    u16*   kh    = (u16*)  take((size_t)MROWS * DIM * 2);
    u16*   vT    = (u16*)  take((size_t)MROWS * DIM * 2);
    u16*   ctx   = (u16*)  take((size_t)MROWS * DIM * 2);
    u16*   h1    = (u16*)  take((size_t)MROWS * DFFN * 2);

    TP tp;
    tp.in[0] = Wg[0]; tp.out[0] = wqkvT;          tp.ls[0] = 3 * SQ;
    tp.in[1] = Wg[1]; tp.out[1] = wqkvT + SQ;     tp.ls[1] = 3 * SQ;
    tp.in[2] = Wg[2]; tp.out[2] = wqkvT + 2 * SQ; tp.ls[2] = 3 * SQ;
    tp.in[3] = Wg[3]; tp.out[3] = woT;            tp.ls[3] = SQ;
    tp.in[4] = Wg[4]; tp.out[4] = wcatT;          tp.ls[4] = 3 * SQ;
    tp.in[5] = Wg[5]; tp.out[5] = wcatT + SQ;     tp.ls[5] = 3 * SQ;
    tp.in[6] = Wg[6]; tp.out[6] = wcatT + 2 * SQ; tp.ls[6] = 3 * SQ;
    tp.in[7] = Wg[7]; tp.out[7] = wocT;           tp.ls[7] = SQ;
    transpose8<<<dim3(16, 16, 8 * NLAY), 256, 0, stream>>>(tp);
    transpose_w<<<dim3(64, 16, NLAY), 256, 0, stream>>>(W1, w1T, DIM, DFFN, (long)DIM * DFFN);
    transpose_w<<<dim3(16, 64, NLAY), 256, 0, stream>>>(W2, w2T, DFFN, DIM, (long)DIM * DFFN);
    concat_bias<<<NLAY * 3 * DIM / 256, 256, 0, stream>>>(bg[0], bg[1], bg[2], bqkv, 3);
    concat_bias<<<NLAY * 3 * DIM / 256, 256, 0, stream>>>(bg[4], bg[5], bg[6], bqkvc, 3);
    conv_f32_bf16<<<2048, 256, 0, stream>>>(memory, memb);
    embed_pe<<<2048, 256, 0, stream>>>(targets, emb, xb);

    const int BIG = 1 << 30;
    for (int i = 0; i < NLAY; ++i) {
        const u16 *wqkv = wqkvT + (long)i * 3 * SQ, *wcat = wcatT + (long)i * 3 * SQ;
        const u16 *wo = woT + (long)i * SQ, *woc = wocT + (long)i * SQ;
        const u16 *w1t = w1T + (long)i * DIM * DFFN, *w2t = w2T + (long)i * DIM * DFFN;
        const float *bo = bg[3] + i * DIM, *boc = bg[7] + i * DIM;

        // ---- self attention (causal) ----
        gemm_t<128, 128, 4><<<384, 256, 0, stream>>>(xb, xb, wqkv, qh, kh, vT, bqkv + i * 3 * DIM, DIM, 0, 12, BIG);
        flash_attn<true><<<BATCH * NHEAD * (SEQ / 64), 256, 0, stream>>>(qh, kh, vT, ctx);
        gemm_t<64, 64, 0><<<512, 256, 0, stream>>>(ctx, ctx, wo, y, nullptr, nullptr, bo, DIM, DIM, 8, BIG);
        add_ln<<<MROWS / 4, 256, 0, stream>>>(xb, y, g1 + i * DIM, be1 + i * DIM, nullptr);

        // ---- cross attention (no mask): fused Q(from xb) | K,V (from memb) ----
        gemm_t<128, 128, 4><<<384, 256, 0, stream>>>(xb, memb, wcat, qh, kh, vT, bqkvc + i * 3 * DIM, DIM, 0, 12, 512);
        flash_attn<false><<<BATCH * NHEAD * (SEQ / 64), 256, 0, stream>>>(qh, kh, vT, ctx);
        gemm_t<64, 64, 0><<<512, 256, 0, stream>>>(ctx, ctx, woc, y, nullptr, nullptr, boc, DIM, DIM, 8, BIG);
        add_ln<<<MROWS / 4, 256, 0, stream>>>(xb, y, g2 + i * DIM, be2 + i * DIM, nullptr);

        // ---- FFN ----
        gemm_t<128, 128, 1><<<512, 256, 0, stream>>>(xb, xb, w1t, h1, nullptr, nullptr, b1 + i * DFFN, DIM, DFFN, 16, BIG);
        gemm_t<64, 64, 0><<<512, 256, 0, stream>>>(h1, h1, w2t, y, nullptr, nullptr, b2 + i * DIM, DFFN, DIM, 8, BIG);
        add_ln<<<MROWS / 4, 256, 0, stream>>>(xb, y, g3 + i * DIM, be3 + i * DIM,
                                              (i == NLAY - 1) ? (float*)d_out : nullptr);
    }
}

// Round 9
// 817.864 us; speedup vs baseline: 1.0176x; 1.0176x over previous
//
#include <hip/hip_runtime.h>

typedef unsigned short u16;
typedef unsigned int   u32;
typedef __attribute__((ext_vector_type(4))) u16   u16x4;
typedef __attribute__((ext_vector_type(8))) u16   u16x8;
typedef __attribute__((ext_vector_type(8))) __bf16 bf16x8;
typedef __attribute__((ext_vector_type(4))) float f32x4;

#define DEV static __device__ __forceinline__

constexpr int DIM = 512, NHEAD = 8, DHEAD = 64, DFFN = 2048, NLAY = 6, SEQ = 512, BATCH = 8;
constexpr int MROWS = BATCH * SEQ;            // 4096 token rows
constexpr long HD = (long)SEQ * DHEAD;        // 32768 per-head q/k/v block
constexpr long SQ = (long)DIM * DIM;          // 262144

DEV float bf2f(u16 u) { union { u32 i; float f; } x; x.i = (u32)u << 16; return x.f; }
DEV u16 f2bf(float f) { union { float f; u32 i; } x; x.f = f; u32 r = x.i + 0x7fffu + ((x.i >> 16) & 1u); return (u16)(r >> 16); }

DEV void gl_lds16(const u16* g, u16* l) {
    __builtin_amdgcn_global_load_lds((const __attribute__((address_space(1))) u32*)(const void*)g,
                                     (__attribute__((address_space(3))) u32*)(void*)l, 16, 0, 0);
}

// ---------------------------------------------------------------------------
// Merged transpose for the 8 square (512x512 per layer) weights.
// ---------------------------------------------------------------------------
struct TP { const float* in[8]; u16* out[8]; long ls[8]; };

__global__ __launch_bounds__(256) void transpose8(TP p)
{
    __shared__ u16 t[32][33];
    int z = blockIdx.z, which = z / NLAY, l = z % NLAY;
    const float* in = p.in[which] + (long)l * SQ;
    u16* out = p.out[which] + (long)l * p.ls[which];
    int k0 = blockIdx.y * 32, n0 = blockIdx.x * 32;
    int tx = threadIdx.x & 31, ty = threadIdx.x >> 5;
    #pragma unroll
    for (int i = ty; i < 32; i += 8) t[i][tx] = f2bf(in[(long)(k0 + i) * 512 + n0 + tx]);
    __syncthreads();
    #pragma unroll
    for (int i = ty; i < 32; i += 8) out[(long)(n0 + i) * 512 + k0 + tx] = t[tx][i];
}

// generic transpose (for W1/W2): out[z*outLS + n*K + k] = bf16(in[z*K*N + k*N + n])
__global__ __launch_bounds__(256) void transpose_w(const float* __restrict__ in, u16* __restrict__ out,
                                                   int K, int N, long outLS)
{
    __shared__ u16 t[32][33];
    long bi = (long)blockIdx.z * K * N, bo = (long)blockIdx.z * outLS;
    int k0 = blockIdx.y * 32, n0 = blockIdx.x * 32;
    int tx = threadIdx.x & 31, ty = threadIdx.x >> 5;
    #pragma unroll
    for (int i = ty; i < 32; i += 8) t[i][tx] = f2bf(in[bi + (long)(k0 + i) * N + n0 + tx]);
    __syncthreads();
    #pragma unroll
    for (int i = ty; i < 32; i += 8) out[bo + (long)(n0 + i) * K + k0 + tx] = t[tx][i];
}

// concat per-layer bias vectors (each NLAY x 512) into [NLAY][nsrc*512]
__global__ __launch_bounds__(256) void concat_bias(const float* __restrict__ a, const float* __restrict__ b,
                                                   const float* __restrict__ c, float* __restrict__ out, int nsrc)
{
    int i = blockIdx.x * 256 + threadIdx.x;
    int col = i & 511, j = (i >> 9) % nsrc, l = i / (nsrc * 512);
    const float* s = (j == 0) ? a : (j == 1) ? b : c;
    out[i] = s[l * 512 + col];
}

__global__ __launch_bounds__(256) void conv_f32_bf16(const float* __restrict__ in, u16* __restrict__ out)
{
    long i = ((long)blockIdx.x * 256 + threadIdx.x) * 4;
    float4 v = *(const float4*)(in + i);
    u16x4 o; o.x = f2bf(v.x); o.y = f2bf(v.y); o.z = f2bf(v.z); o.w = f2bf(v.w);
    *(u16x4*)(out + i) = o;
}

// ---------------------------------------------------------------------------
// Embedding * sqrt(D) + sinusoidal positional encoding -> xb (bf16 residual)
// ---------------------------------------------------------------------------
__global__ __launch_bounds__(256) void embed_pe(const int* __restrict__ targets, const float* __restrict__ emb,
                                                u16* __restrict__ xb)
{
    int t4 = (blockIdx.x * 256 + threadIdx.x) * 4;
    int d = t4 & (DIM - 1);
    int s = (t4 >> 9) & (SEQ - 1);
    int b = t4 >> 18;
    int tok = targets[s * BATCH + b];
    float4 e = *(const float4*)(emb + (long)tok * DIM + d);
    u16x4 ob;
    const float ef[4] = { e.x, e.y, e.z, e.w };
    #pragma unroll
    for (int j = 0; j < 4; ++j) {
        int dd = d + j;
        float div = expf((float)(dd & ~1) * -0.017988946039016f);  // -ln(10000)/512
        float ang = (float)s * div;
        float pe = (dd & 1) ? cosf(ang) : sinf(ang);
        ob[j] = f2bf(ef[j] * 22.627416997969522f + pe);            // sqrt(512)
    }
    *(u16x4*)(xb + ((long)b * SEQ + s) * DIM + d) = ob;
}

// scatter helpers: (B*S, D)-indexed value -> head-split layouts
DEV void scat_sd(u16* dst, int mm, int col, float v) {   // (B,NH,S,DH)
    dst[(long)((mm >> 9) * NHEAD + (col >> 6)) * HD + (long)(mm & 511) * DHEAD + (col & 63)] = f2bf(v);
}
DEV void scat_ds(u16* dst, int mm, int col, float v) {   // (B,NH,DH,S)
    dst[(long)((mm >> 9) * NHEAD + (col >> 6)) * HD + (long)(col & 63) * SEQ + (mm & 511)] = f2bf(v);
}

// ---------------------------------------------------------------------------
// GEMM: C = A @ Bt^T + bias.  BM x BN tile, BK=64, 4 waves (wave BM/2 x BN/2).
// global_load_lds width-16 into linear LDS, double-buffered, one barrier per
// K-step (R7-proven structure). Both-sides XOR swizzle keeps ds_read_b128
// conflict-free. Row stride `ld` decoupled from K-loop length `K` to support
// split-K: grid.y = split index s, covering K-window [s*K, (s+1)*K).
// A pointer per block: n0 < aSplit ? A0 : A1 (fused cross Q|K|V).
// 1D grid.x + bijective XCD-chunk swizzle (grid.x % 8 == 0).
// EPI: 0=bf16 plain, 1=bf16+relu, 4=QKV head-split scatter,
//      5=f32 partial (no bias) at C0 + s*MROWS*ldc   (split-K)
// ---------------------------------------------------------------------------
template <int BM, int BN, int EPI>
__global__ __launch_bounds__(256) void gemm_t(const u16* __restrict__ A0, const u16* __restrict__ A1,
                                              const u16* __restrict__ Bt,
                                              void* __restrict__ C0, void* __restrict__ C1, void* __restrict__ C2,
                                              const float* __restrict__ bias, int K, int ld, int ldc,
                                              int gx, int aSplit)
{
    constexpr int NCHA = BM / 8;          // 8-row A chunks
    constexpr int NCH  = (BM + BN) / 8;   // total chunks per buffer
    constexpr int MI   = BM / 32;         // M frags per wave
    constexpr int NI   = BN / 32;         // N frags per wave
    __shared__ __align__(16) u16 lds[2][NCH * 512];

    const int tid = threadIdx.x, lane = tid & 63, wid = tid >> 6;
    const int nwg = gridDim.x, bid = blockIdx.x;
    const int wg = (bid & 7) * (nwg >> 3) + (bid >> 3);     // XCD-chunk swizzle
    const int m0 = (wg / gx) * BM, n0 = (wg % gx) * BN;
    const u16* A = (n0 < aSplit) ? A0 : A1;
    const int kBase = blockIdx.y * K;                        // split-K window
    const int wr = (wid >> 1) * (BM / 2), wc = (wid & 1) * (BN / 2);
    const int fr = lane & 15, fq = lane >> 4;
    const int srow = lane >> 3;                              // 0..7 row in chunk
    const int scol = ((lane & 7) ^ srow) * 8;                // pre-swizzled source col

    f32x4 acc[MI][NI] = {};

    auto stage = [&](int buf, int k0) {
        #pragma unroll
        for (int c = wid; c < NCH; c += 4) {
            if (c < NCHA) gl_lds16(A  + (long)(m0 + c * 8 + srow) * ld + kBase + k0 + scol, &lds[buf][c * 512]);
            else          gl_lds16(Bt + (long)(n0 + (c - NCHA) * 8 + srow) * ld + kBase + k0 + scol, &lds[buf][c * 512]);
        }
    };

    const int nt = K >> 6;
    stage(0, 0);
    __syncthreads();                        // drains vmcnt(0): buf0 ready
    int cur = 0;
    const int swz = (fr & 7) << 4;
    for (int t = 0; t < nt; ++t) {
        if (t + 1 < nt) stage(cur ^ 1, (t + 1) << 6);
        const char* lb = (const char*)&lds[cur][0];
        bf16x8 a[MI][2], b[NI][2];
        #pragma unroll
        for (int mi = 0; mi < MI; ++mi)
            #pragma unroll
            for (int kk = 0; kk < 2; ++kk)
                a[mi][kk] = *(const bf16x8*)(lb + (wr + mi * 16 + fr) * 128 + ((kk * 64 + fq * 16) ^ swz));
        #pragma unroll
        for (int ni = 0; ni < NI; ++ni)
            #pragma unroll
            for (int kk = 0; kk < 2; ++kk)
                b[ni][kk] = *(const bf16x8*)(lb + (BM + wc + ni * 16 + fr) * 128 + ((kk * 64 + fq * 16) ^ swz));
        #pragma unroll
        for (int kk = 0; kk < 2; ++kk)
            #pragma unroll
            for (int mi = 0; mi < MI; ++mi)
                #pragma unroll
                for (int ni = 0; ni < NI; ++ni)
                    acc[mi][ni] = __builtin_amdgcn_mfma_f32_16x16x32_bf16(a[mi][kk], b[ni][kk], acc[mi][ni], 0, 0, 0);
        __syncthreads();
        cur ^= 1;
    }

    #pragma unroll
    for (int mi = 0; mi < MI; ++mi)
    #pragma unroll
    for (int ni = 0; ni < NI; ++ni)
    #pragma unroll
    for (int rr = 0; rr < 4; ++rr) {
        int mm = m0 + wr + mi * 16 + fq * 4 + rr;
        int nn = n0 + wc + ni * 16 + fr;
        float v = acc[mi][ni][rr];
        if (EPI != 5) v += bias[nn];
        if (EPI == 0) {
            ((u16*)C0)[(long)mm * ldc + nn] = f2bf(v);
        } else if (EPI == 1) {
            ((u16*)C0)[(long)mm * ldc + nn] = f2bf(fmaxf(v, 0.f));
        } else if (EPI == 5) {
            ((float*)C0)[(long)blockIdx.y * MROWS * ldc + (long)mm * ldc + nn] = v;
        } else {            // QKV head-split
            int which = nn >> 9, col = nn & 511;
            if (which == 0)      scat_sd((u16*)C0, mm, col, v);
            else if (which == 1) scat_sd((u16*)C1, mm, col, v);
            else                 scat_ds((u16*)C2, mm, col, v);
        }
    }
}

// ---------------------------------------------------------------------------
// Flash attention: block = (head = bid & 63, qt = bid >> 6) so all 8 q-tiles
// of a head land on ONE XCD. 4 waves x 16 q-rows. KV tiles of 128, double-
// buffered LDS, both-sides XOR swizzle on K and V. Online softmax in C-layout
// registers; P via swizzled per-wave LDS slab. setprio around MFMA.
// ---------------------------------------------------------------------------
template <bool CAUSAL>
__global__ __launch_bounds__(256) void flash_attn(const u16* __restrict__ qh, const u16* __restrict__ kh,
                                                  const u16* __restrict__ vT, u16* __restrict__ ctx)
{
    constexpr int KVB = 128;
    __shared__ __align__(16) u16 Kl[2][KVB * 64];    // kv x dh, swizzled
    __shared__ __align__(16) u16 Vl[2][64 * KVB];    // dh x kv, swizzled
    __shared__ __align__(16) u16 Pl[4][16 * KVB];    // per-wave P, swizzled
    const int lane = threadIdx.x & 63, wid = threadIdx.x >> 6;
    const int head = blockIdx.x & 63, qt = blockIdx.x >> 6;   // head-major: XCD = head%8
    const int q0 = qt * 64;
    const long hb = (long)head * HD;
    const int fr = lane & 15, fq = lane >> 4;
    const int swz = (fr & 7) << 4;

    bf16x8 qf[2];
    #pragma unroll
    for (int kf = 0; kf < 2; ++kf)
        qf[kf] = *(const bf16x8*)(qh + hb + (long)(q0 + wid * 16 + fr) * 64 + kf * 32 + fq * 8);

    const int nt = CAUSAL ? (q0 >> 7) + 1 : SEQ / KVB;

    auto stage = [&](int buf, int t) {
        const long kv0 = (long)t * KVB;
        const int kr = lane >> 3;                        // K: 8 rows/chunk
        const int kcol = ((lane & 7) ^ kr) * 8;
        for (int c = wid; c < 16; c += 4)
            gl_lds16(kh + hb + (kv0 + c * 8 + kr) * 64 + kcol, &Kl[buf][c * 512]);
        const int vr = lane >> 4;                        // V^T: 4 rows/chunk
        for (int c = wid; c < 16; c += 4) {
            int row = c * 4 + vr;
            int vcol = ((lane & 15) ^ (row & 7)) * 8;
            gl_lds16(vT + hb + (long)row * SEQ + kv0 + vcol, &Vl[buf][c * 512]);
        }
    };

    float m[4], l[4];
    #pragma unroll
    for (int r = 0; r < 4; ++r) { m[r] = -3.0e38f; l[r] = 0.f; }
    f32x4 ao[4] = {};

    stage(0, 0);
    __syncthreads();
    int cur = 0;
    for (int t = 0; t < nt; ++t) {
        if (t + 1 < nt) stage(cur ^ 1, t + 1);
        f32x4 as[8] = {};
        const char* kb = (const char*)&Kl[cur][0];
        __builtin_amdgcn_s_setprio(1);
        #pragma unroll
        for (int nf = 0; nf < 8; ++nf)
            #pragma unroll
            for (int kf = 0; kf < 2; ++kf) {
                bf16x8 kfr = *(const bf16x8*)(kb + (nf * 16 + fr) * 128 + ((kf * 64 + fq * 16) ^ swz));
                as[nf] = __builtin_amdgcn_mfma_f32_16x16x32_bf16(qf[kf], kfr, as[nf], 0, 0, 0);
            }
        __builtin_amdgcn_s_setprio(0);
        const int kv0 = t * KVB;
        const int qrow = q0 + wid * 16 + fq * 4;
        #pragma unroll
        for (int nf = 0; nf < 8; ++nf)
            #pragma unroll
            for (int rr = 0; rr < 4; ++rr) {
                float s = as[nf][rr] * 0.125f;
                if (CAUSAL && (kv0 + nf * 16 + fr > qrow + rr)) s = -3.0e38f;
                as[nf][rr] = s;
            }
        float p_scale[4];
        #pragma unroll
        for (int rr = 0; rr < 4; ++rr) {
            float mx = as[0][rr];
            #pragma unroll
            for (int nf = 1; nf < 8; ++nf) mx = fmaxf(mx, as[nf][rr]);
            #pragma unroll
            for (int o = 1; o < 16; o <<= 1) mx = fmaxf(mx, __shfl_xor(mx, o, 64));
            float mnew = fmaxf(m[rr], mx);
            p_scale[rr] = __expf(m[rr] - mnew);
            m[rr] = mnew;
        }
        float rsum[4] = {0.f, 0.f, 0.f, 0.f};
        u16* pw = &Pl[wid][0];
        #pragma unroll
        for (int nf = 0; nf < 8; ++nf)
            #pragma unroll
            for (int rr = 0; rr < 4; ++rr) {
                float p = __expf(as[nf][rr] - m[rr]);
                rsum[rr] += p;
                int row = fq * 4 + rr;
                int byte = (row * 256 + (nf * 16 + fr) * 2) ^ ((row & 7) << 4);
                *(u16*)((char*)pw + byte) = f2bf(p);
            }
        #pragma unroll
        for (int rr = 0; rr < 4; ++rr) {
            #pragma unroll
            for (int o = 1; o < 16; o <<= 1) rsum[rr] += __shfl_xor(rsum[rr], o, 64);
            l[rr] = l[rr] * p_scale[rr] + rsum[rr];
        }
        #pragma unroll
        for (int nf = 0; nf < 4; ++nf)
            #pragma unroll
            for (int rr = 0; rr < 4; ++rr) ao[nf][rr] *= p_scale[rr];
        const char* vb = (const char*)&Vl[cur][0];
        __builtin_amdgcn_s_setprio(1);
        #pragma unroll
        for (int kf = 0; kf < 4; ++kf) {
            int pbyte = (fr * 256 + kf * 64 + fq * 16) ^ swz;
            bf16x8 pa = *(const bf16x8*)((const char*)pw + pbyte);
            #pragma unroll
            for (int nf = 0; nf < 4; ++nf) {
                bf16x8 vf = *(const bf16x8*)(vb + (nf * 16 + fr) * 256 + ((kf * 64 + fq * 16) ^ swz));
                ao[nf] = __builtin_amdgcn_mfma_f32_16x16x32_bf16(pa, vf, ao[nf], 0, 0, 0);
            }
        }
        __builtin_amdgcn_s_setprio(0);
        __syncthreads();
        cur ^= 1;
    }
    const int b = head >> 3, h = head & 7;
    #pragma unroll
    for (int nf = 0; nf < 4; ++nf)
        #pragma unroll
        for (int rr = 0; rr < 4; ++rr) {
            int qq = q0 + wid * 16 + fq * 4 + rr;
            ctx[((long)(b * SEQ + qq)) * DIM + h * 64 + nf * 16 + fr] = f2bf(ao[nf][rr] / l[rr]);
        }
}

// ---------------------------------------------------------------------------
// xb = LayerNorm(xb + y) * g + be, in place (y bf16).
// ---------------------------------------------------------------------------
__global__ __launch_bounds__(256) void add_ln(u16* xb, const u16* __restrict__ y,
                                              const float* __restrict__ g, const float* __restrict__ be)
{
    int row = blockIdx.x * 4 + (threadIdx.x >> 6);
    int lane = threadIdx.x & 63;
    long off = (long)row * DIM + lane * 8;
    u16x8 xv = *(const u16x8*)(xb + off);
    u16x8 yv = *(const u16x8*)(y + off);
    float v[8];
    #pragma unroll
    for (int j = 0; j < 8; ++j) v[j] = bf2f(xv[j]) + bf2f(yv[j]);
    float sum = 0.f;
    #pragma unroll
    for (int j = 0; j < 8; ++j) sum += v[j];
    #pragma unroll
    for (int o = 32; o; o >>= 1) sum += __shfl_xor(sum, o, 64);
    float mean = sum * (1.0f / DIM);
    float vs = 0.f;
    #pragma unroll
    for (int j = 0; j < 8; ++j) { float d = v[j] - mean; vs += d * d; }
    #pragma unroll
    for (int o = 32; o; o >>= 1) vs += __shfl_xor(vs, o, 64);
    float rstd = rsqrtf(vs * (1.0f / DIM) + 1e-5f);
    u16x8 ob;
    #pragma unroll
    for (int j = 0; j < 8; ++j) {
        int col = lane * 8 + j;
        ob[j] = f2bf((v[j] - mean) * rstd * g[col] + be[col]);
    }
    *(u16x8*)(xb + off) = ob;
}

// ---------------------------------------------------------------------------
// xb = LayerNorm(xb + y0 + y1 + bias) * g + be  (split-K f32 partials reduce).
// If xf != nullptr, also write f32 copy (final output).
// ---------------------------------------------------------------------------
__global__ __launch_bounds__(256) void add_ln2(u16* xb, const float* __restrict__ yf,
                                               const float* __restrict__ bias,
                                               const float* __restrict__ g, const float* __restrict__ be,
                                               float* __restrict__ xf)
{
    int row = blockIdx.x * 4 + (threadIdx.x >> 6);
    int lane = threadIdx.x & 63;
    long off = (long)row * DIM + lane * 8;
    u16x8 xv = *(const u16x8*)(xb + off);
    float4 a0 = *(const float4*)(yf + off);
    float4 a1 = *(const float4*)(yf + off + 4);
    float4 b0 = *(const float4*)(yf + (long)MROWS * DIM + off);
    float4 b1 = *(const float4*)(yf + (long)MROWS * DIM + off + 4);
    float v[8] = { a0.x + b0.x, a0.y + b0.y, a0.z + b0.z, a0.w + b0.w,
                   a1.x + b1.x, a1.y + b1.y, a1.z + b1.z, a1.w + b1.w };
    #pragma unroll
    for (int j = 0; j < 8; ++j) v[j] += bf2f(xv[j]) + bias[lane * 8 + j];
    float sum = 0.f;
    #pragma unroll
    for (int j = 0; j < 8; ++j) sum += v[j];
    #pragma unroll
    for (int o = 32; o; o >>= 1) sum += __shfl_xor(sum, o, 64);
    float mean = sum * (1.0f / DIM);
    float vs = 0.f;
    #pragma unroll
    for (int j = 0; j < 8; ++j) { float d = v[j] - mean; vs += d * d; }
    #pragma unroll
    for (int o = 32; o; o >>= 1) vs += __shfl_xor(vs, o, 64);
    float rstd = rsqrtf(vs * (1.0f / DIM) + 1e-5f);
    float outv[8]; u16x8 ob;
    #pragma unroll
    for (int j = 0; j < 8; ++j) {
        int col = lane * 8 + j;
        float r = (v[j] - mean) * rstd * g[col] + be[col];
        outv[j] = r; ob[j] = f2bf(r);
    }
    *(u16x8*)(xb + off) = ob;
    if (xf) {
        *(float4*)(xf + off)     = *(const float4*)&outv[0];
        *(float4*)(xf + off + 4) = *(const float4*)&outv[4];
    }
}

// ---------------------------------------------------------------------------
extern "C" void kernel_launch(void* const* d_in, const int* in_sizes, int n_in,
                              void* d_out, int out_size, void* d_ws, size_t ws_size,
                              hipStream_t stream)
{
    const int*   targets = (const int*)  d_in[0];
    const float* memory  = (const float*)d_in[1];
    // d_in[2]=trg_mask (causal, analytic), d_in[3]=memory_mask (all false) -> unread
    const float* emb     = (const float*)d_in[4];
    const float* Wg[8]; for (int i = 0; i < 8; ++i) Wg[i] = (const float*)d_in[5 + i];
    const float* bg[8]; for (int i = 0; i < 8; ++i) bg[i] = (const float*)d_in[13 + i];
    const float* W1  = (const float*)d_in[21];
    const float* b1  = (const float*)d_in[22];
    const float* W2  = (const float*)d_in[23];
    const float* b2  = (const float*)d_in[24];
    const float* g1  = (const float*)d_in[25];
    const float* g2  = (const float*)d_in[26];
    const float* g3  = (const float*)d_in[27];
    const float* be1 = (const float*)d_in[28];
    const float* be2 = (const float*)d_in[29];
    const float* be3 = (const float*)d_in[30];

    char* w = (char*)d_ws;
    auto take = [&](size_t n) -> char* { char* p = w; w += (n + 255) & ~(size_t)255; return p; };
    u16*   wqkvT = (u16*)take((size_t)NLAY * 3 * SQ * 2);   // self  [L][1536][512]
    u16*   wcatT = (u16*)take((size_t)NLAY * 3 * SQ * 2);   // cross [L][1536][512]
    u16*   woT   = (u16*)take((size_t)NLAY * SQ * 2);
    u16*   wocT  = (u16*)take((size_t)NLAY * SQ * 2);
    u16*   w1T   = (u16*)take((size_t)NLAY * DIM * DFFN * 2);
    u16*   w2T   = (u16*)take((size_t)NLAY * DIM * DFFN * 2);
    float* bqkv  = (float*)take((size_t)NLAY * 3 * DIM * 4);
    float* bqkvc = (float*)take((size_t)NLAY * 3 * DIM * 4);
    u16*   xb    = (u16*)  take((size_t)MROWS * DIM * 2);   // bf16 residual stream
    u16*   y     = (u16*)  take((size_t)MROWS * DIM * 2);
    float* yf    = (float*)take((size_t)2 * MROWS * DIM * 4); // split-K f32 partials
    u16*   memb  = (u16*)  take((size_t)MROWS * DIM * 2);
    u16*   qh    = (u16*)  take((size_t)MROWS * DIM * 2);
    u16*   kh    = (u16*)  take((size_t)MROWS * DIM * 2);
    u16*   vT    = (u16*)  take((size_t)MROWS * DIM * 2);
    u16*   ctx   = (u16*)  take((size_t)MROWS * DIM * 2);
    u16*   h1    = (u16*)  take((size_t)MROWS * DFFN * 2);

    TP tp;
    tp.in[0] = Wg[0]; tp.out[0] = wqkvT;          tp.ls[0] = 3 * SQ;
    tp.in[1] = Wg[1]; tp.out[1] = wqkvT + SQ;     tp.ls[1] = 3 * SQ;
    tp.in[2] = Wg[2]; tp.out[2] = wqkvT + 2 * SQ; tp.ls[2] = 3 * SQ;
    tp.in[3] = Wg[3]; tp.out[3] = woT;            tp.ls[3] = SQ;
    tp.in[4] = Wg[4]; tp.out[4] = wcatT;          tp.ls[4] = 3 * SQ;
    tp.in[5] = Wg[5]; tp.out[5] = wcatT + SQ;     tp.ls[5] = 3 * SQ;
    tp.in[6] = Wg[6]; tp.out[6] = wcatT + 2 * SQ; tp.ls[6] = 3 * SQ;
    tp.in[7] = Wg[7]; tp.out[7] = wocT;           tp.ls[7] = SQ;
    transpose8<<<dim3(16, 16, 8 * NLAY), 256, 0, stream>>>(tp);
    transpose_w<<<dim3(64, 16, NLAY), 256, 0, stream>>>(W1, w1T, DIM, DFFN, (long)DIM * DFFN);
    transpose_w<<<dim3(16, 64, NLAY), 256, 0, stream>>>(W2, w2T, DFFN, DIM, (long)DIM * DFFN);
    concat_bias<<<NLAY * 3 * DIM / 256, 256, 0, stream>>>(bg[0], bg[1], bg[2], bqkv, 3);
    concat_bias<<<NLAY * 3 * DIM / 256, 256, 0, stream>>>(bg[4], bg[5], bg[6], bqkvc, 3);
    conv_f32_bf16<<<2048, 256, 0, stream>>>(memory, memb);
    embed_pe<<<2048, 256, 0, stream>>>(targets, emb, xb);

    const int BIG = 1 << 30;
    for (int i = 0; i < NLAY; ++i) {
        const u16 *wqkv = wqkvT + (long)i * 3 * SQ, *wcat = wcatT + (long)i * 3 * SQ;
        const u16 *wo = woT + (long)i * SQ, *woc = wocT + (long)i * SQ;
        const u16 *w1t = w1T + (long)i * DIM * DFFN, *w2t = w2T + (long)i * DIM * DFFN;
        const float *bo = bg[3] + i * DIM, *boc = bg[7] + i * DIM;

        // ---- self attention (causal) ----
        gemm_t<128, 128, 4><<<384, 256, 0, stream>>>(xb, xb, wqkv, qh, kh, vT, bqkv + i * 3 * DIM, DIM, DIM, 0, 12, BIG);
        flash_attn<true><<<BATCH * NHEAD * (SEQ / 64), 256, 0, stream>>>(qh, kh, vT, ctx);
        gemm_t<64, 64, 0><<<512, 256, 0, stream>>>(ctx, ctx, wo, y, nullptr, nullptr, bo, DIM, DIM, DIM, 8, BIG);
        add_ln<<<MROWS / 4, 256, 0, stream>>>(xb, y, g1 + i * DIM, be1 + i * DIM);

        // ---- cross attention (no mask): fused Q(from xb) | K,V (from memb) ----
        gemm_t<128, 128, 4><<<384, 256, 0, stream>>>(xb, memb, wcat, qh, kh, vT, bqkvc + i * 3 * DIM, DIM, DIM, 0, 12, 512);
        flash_attn<false><<<BATCH * NHEAD * (SEQ / 64), 256, 0, stream>>>(qh, kh, vT, ctx);
        gemm_t<64, 64, 0><<<512, 256, 0, stream>>>(ctx, ctx, woc, y, nullptr, nullptr, boc, DIM, DIM, DIM, 8, BIG);
        add_ln<<<MROWS / 4, 256, 0, stream>>>(xb, y, g2 + i * DIM, be2 + i * DIM);

        // ---- FFN ----
        gemm_t<128, 128, 1><<<512, 256, 0, stream>>>(xb, xb, w1t, h1, nullptr, nullptr, b1 + i * DFFN, DIM, DIM, DFFN, 16, BIG);
        // FFN2 split-K=2: grid (512, 2); f32 partials into yf; bias+reduce fused in add_ln2
        gemm_t<64, 64, 5><<<dim3(512, 2), 256, 0, stream>>>(h1, h1, w2t, yf, nullptr, nullptr, nullptr,
                                                            DFFN / 2, DFFN, DIM, 8, BIG);
        add_ln2<<<MROWS / 4, 256, 0, stream>>>(xb, yf, b2 + i * DIM, g3 + i * DIM, be3 + i * DIM,
                                               (i == NLAY - 1) ? (float*)d_out : nullptr);
    }
}

// Round 10
// 813.820 us; speedup vs baseline: 1.0226x; 1.0050x over previous
//
#include <hip/hip_runtime.h>

typedef unsigned short u16;
typedef unsigned int   u32;
typedef __attribute__((ext_vector_type(4))) u16   u16x4;
typedef __attribute__((ext_vector_type(8))) u16   u16x8;
typedef __attribute__((ext_vector_type(8))) __bf16 bf16x8;
typedef __attribute__((ext_vector_type(4))) float f32x4;

#define DEV static __device__ __forceinline__

constexpr int DIM = 512, NHEAD = 8, DHEAD = 64, DFFN = 2048, NLAY = 6, SEQ = 512, BATCH = 8;
constexpr int MROWS = BATCH * SEQ;            // 4096 token rows
constexpr long HD = (long)SEQ * DHEAD;        // 32768 per-head q/k/v block
constexpr long SQ = (long)DIM * DIM;          // 262144

DEV float bf2f(u16 u) { union { u32 i; float f; } x; x.i = (u32)u << 16; return x.f; }
DEV u16 f2bf(float f) { union { float f; u32 i; } x; x.f = f; u32 r = x.i + 0x7fffu + ((x.i >> 16) & 1u); return (u16)(r >> 16); }

DEV void gl_lds16(const u16* g, u16* l) {
    __builtin_amdgcn_global_load_lds((const __attribute__((address_space(1))) u32*)(const void*)g,
                                     (__attribute__((address_space(3))) u32*)(void*)l, 16, 0, 0);
}

// ---------------------------------------------------------------------------
// Merged transpose for the 8 square (512x512 per layer) weights.
// ---------------------------------------------------------------------------
struct TP { const float* in[8]; u16* out[8]; long ls[8]; };

__global__ __launch_bounds__(256) void transpose8(TP p)
{
    __shared__ u16 t[32][33];
    int z = blockIdx.z, which = z / NLAY, l = z % NLAY;
    const float* in = p.in[which] + (long)l * SQ;
    u16* out = p.out[which] + (long)l * p.ls[which];
    int k0 = blockIdx.y * 32, n0 = blockIdx.x * 32;
    int tx = threadIdx.x & 31, ty = threadIdx.x >> 5;
    #pragma unroll
    for (int i = ty; i < 32; i += 8) t[i][tx] = f2bf(in[(long)(k0 + i) * 512 + n0 + tx]);
    __syncthreads();
    #pragma unroll
    for (int i = ty; i < 32; i += 8) out[(long)(n0 + i) * 512 + k0 + tx] = t[tx][i];
}

// W1 (512x2048) and W2 (2048x512) transposes merged: grid (64, 16, 2*NLAY).
__global__ __launch_bounds__(256) void transpose_w12(const float* __restrict__ W1, const float* __restrict__ W2,
                                                     u16* __restrict__ w1T, u16* __restrict__ w2T)
{
    __shared__ u16 t[32][33];
    int z = blockIdx.z;
    bool isW2 = z >= NLAY;
    int l = isW2 ? z - NLAY : z;
    const float* in = (isW2 ? W2 : W1) + (long)l * DIM * DFFN;
    u16* out = (isW2 ? w2T : w1T) + (long)l * DIM * DFFN;
    int K = isW2 ? DFFN : DIM, N = isW2 ? DIM : DFFN;
    int k0 = (isW2 ? blockIdx.x : blockIdx.y) * 32;
    int n0 = (isW2 ? blockIdx.y : blockIdx.x) * 32;
    int tx = threadIdx.x & 31, ty = threadIdx.x >> 5;
    #pragma unroll
    for (int i = ty; i < 32; i += 8) t[i][tx] = f2bf(in[(long)(k0 + i) * N + n0 + tx]);
    __syncthreads();
    #pragma unroll
    for (int i = ty; i < 32; i += 8) out[(long)(n0 + i) * K + k0 + tx] = t[tx][i];
}

// both bias concats in one dispatch: [NLAY][1536] each, grid 72.
struct CB { const float* s[6]; };
__global__ __launch_bounds__(256) void concat2(CB p, float* __restrict__ bqkv, float* __restrict__ bqkvc)
{
    int i = blockIdx.x * 256 + threadIdx.x;
    constexpr int HALF = NLAY * 3 * DIM;   // 9216
    int j = (i < HALF) ? i : i - HALF;
    int col = j & 511, wsel = (j >> 9) % 3, l = j / 1536;
    const float* s = p.s[(i < HALF ? 0 : 3) + wsel];
    (i < HALF ? bqkv : bqkvc)[j] = s[l * 512 + col];
}

// ---------------------------------------------------------------------------
// Embedding + PE (blocks 0..2047) and memory f32->bf16 (blocks 2048..4095).
// ---------------------------------------------------------------------------
__global__ __launch_bounds__(256) void prep_act(const int* __restrict__ targets, const float* __restrict__ emb,
                                                u16* __restrict__ xb,
                                                const float* __restrict__ memory, u16* __restrict__ memb)
{
    int bid = blockIdx.x;
    if (bid < 2048) {
        int t4 = (bid * 256 + threadIdx.x) * 4;
        int d = t4 & (DIM - 1);
        int s = (t4 >> 9) & (SEQ - 1);
        int b = t4 >> 18;
        int tok = targets[s * BATCH + b];
        float4 e = *(const float4*)(emb + (long)tok * DIM + d);
        u16x4 ob;
        const float ef[4] = { e.x, e.y, e.z, e.w };
        #pragma unroll
        for (int j = 0; j < 4; ++j) {
            int dd = d + j;
            float div = expf((float)(dd & ~1) * -0.017988946039016f);  // -ln(10000)/512
            float ang = (float)s * div;
            float pe = (dd & 1) ? cosf(ang) : sinf(ang);
            ob[j] = f2bf(ef[j] * 22.627416997969522f + pe);            // sqrt(512)
        }
        *(u16x4*)(xb + ((long)b * SEQ + s) * DIM + d) = ob;
    } else {
        long i = ((long)(bid - 2048) * 256 + threadIdx.x) * 4;
        float4 v = *(const float4*)(memory + i);
        u16x4 o; o.x = f2bf(v.x); o.y = f2bf(v.y); o.z = f2bf(v.z); o.w = f2bf(v.w);
        *(u16x4*)(memb + i) = o;
    }
}

// scatter helpers: (B*S, D)-indexed value -> head-split layouts
DEV void scat_sd(u16* dst, int mm, int col, float v) {   // (B,NH,S,DH)
    dst[(long)((mm >> 9) * NHEAD + (col >> 6)) * HD + (long)(mm & 511) * DHEAD + (col & 63)] = f2bf(v);
}
DEV void scat_ds(u16* dst, int mm, int col, float v) {   // (B,NH,DH,S)
    dst[(long)((mm >> 9) * NHEAD + (col >> 6)) * HD + (long)(col & 63) * SEQ + (mm & 511)] = f2bf(v);
}

// ---------------------------------------------------------------------------
// GEMM: C = A @ Bt^T + bias.  BM x BN tile, BK in {64,128}, 4 waves
// (wave BM/2 x BN/2). global_load_lds width-16 into linear LDS, double-
// buffered, one barrier per K-step. Both-sides XOR swizzle: LDS rows are
// BK elems (BK*2 bytes = SLOTS 16B slots); stage source slot = (lane%SLOTS)
// ^ (row & (SLOTS-1)); read slot = (kk*4+fq) ^ (row & (SLOTS-1)).
// Row stride `ld` decoupled from K-window `K` (split-K via blockIdx.y).
// EPI: 0=bf16 plain, 1=bf16+relu, 4=QKV head-split scatter,
//      5=f32 partial (no bias) at C0 + blockIdx.y*MROWS*ldc   (split-K)
// ---------------------------------------------------------------------------
template <int BM, int BN, int BK, int EPI>
__global__ __launch_bounds__(256) void gemm_t(const u16* __restrict__ A0, const u16* __restrict__ A1,
                                              const u16* __restrict__ Bt,
                                              void* __restrict__ C0, void* __restrict__ C1, void* __restrict__ C2,
                                              const float* __restrict__ bias, int K, int ld, int ldc,
                                              int gx, int aSplit)
{
    constexpr int SLOTS = BK / 8;          // 16B slots per LDS row (8 or 16)
    constexpr int RPC   = 512 / BK;        // rows per 512-elem chunk (8 or 4)
    constexpr int KK    = BK / 32;         // k-slices per K-step
    constexpr int NCHA  = BM / RPC;        // A chunks
    constexpr int NCH   = (BM + BN) / RPC; // total chunks per buffer
    constexpr int MI    = BM / 32;         // M frags per wave
    constexpr int NI    = BN / 32;         // N frags per wave
    __shared__ __align__(16) u16 lds[2][NCH * 512];

    const int tid = threadIdx.x, lane = tid & 63, wid = tid >> 6;
    const int nwg = gridDim.x, bid = blockIdx.x;
    const int wg = (bid & 7) * (nwg >> 3) + (bid >> 3);     // XCD-chunk swizzle
    const int m0 = (wg / gx) * BM, n0 = (wg % gx) * BN;
    const u16* A = (n0 < aSplit) ? A0 : A1;
    const int kBase = blockIdx.y * K;                        // split-K window
    const int wr = (wid >> 1) * (BM / 2), wc = (wid & 1) * (BN / 2);
    const int fr = lane & 15, fq = lane >> 4;
    const int srow  = lane / SLOTS;                          // row in chunk
    const int sslot = lane % SLOTS;

    f32x4 acc[MI][NI] = {};

    auto stage = [&](int buf, int k0) {
        #pragma unroll
        for (int c = wid; c < NCH; c += 4) {
            int slot = sslot ^ ((c * RPC + srow) & (SLOTS - 1));   // pre-swizzled source slot
            long row = (c < NCHA) ? (long)(m0 + c * RPC + srow)
                                  : (long)(n0 + (c - NCHA) * RPC + srow);
            const u16* src = (c < NCHA) ? A : Bt;
            gl_lds16(src + row * ld + kBase + k0 + slot * 8, &lds[buf][c * 512]);
        }
    };

    const int nt = K / BK;
    stage(0, 0);
    __syncthreads();                        // drains vmcnt(0): buf0 ready
    int cur = 0;
    const int swz = (fr & (SLOTS - 1)) << 4;   // read-side swizzle (row&(SLOTS-1)) == fr&... (wr,wc,mi*16 are 16-multiples)
    for (int t = 0; t < nt; ++t) {
        if (t + 1 < nt) stage(cur ^ 1, (t + 1) * BK);
        const char* lb = (const char*)&lds[cur][0];
        bf16x8 a[MI][KK], b[NI][KK];
        #pragma unroll
        for (int mi = 0; mi < MI; ++mi)
            #pragma unroll
            for (int kk = 0; kk < KK; ++kk)
                a[mi][kk] = *(const bf16x8*)(lb + (wr + mi * 16 + fr) * (BK * 2) + ((kk * 64 + fq * 16) ^ swz));
        #pragma unroll
        for (int ni = 0; ni < NI; ++ni)
            #pragma unroll
            for (int kk = 0; kk < KK; ++kk)
                b[ni][kk] = *(const bf16x8*)(lb + (BM + wc + ni * 16 + fr) * (BK * 2) + ((kk * 64 + fq * 16) ^ swz));
        #pragma unroll
        for (int kk = 0; kk < KK; ++kk)
            #pragma unroll
            for (int mi = 0; mi < MI; ++mi)
                #pragma unroll
                for (int ni = 0; ni < NI; ++ni)
                    acc[mi][ni] = __builtin_amdgcn_mfma_f32_16x16x32_bf16(a[mi][kk], b[ni][kk], acc[mi][ni], 0, 0, 0);
        __syncthreads();
        cur ^= 1;
    }

    #pragma unroll
    for (int mi = 0; mi < MI; ++mi)
    #pragma unroll
    for (int ni = 0; ni < NI; ++ni)
    #pragma unroll
    for (int rr = 0; rr < 4; ++rr) {
        int mm = m0 + wr + mi * 16 + fq * 4 + rr;
        int nn = n0 + wc + ni * 16 + fr;
        float v = acc[mi][ni][rr];
        if (EPI != 5) v += bias[nn];
        if (EPI == 0) {
            ((u16*)C0)[(long)mm * ldc + nn] = f2bf(v);
        } else if (EPI == 1) {
            ((u16*)C0)[(long)mm * ldc + nn] = f2bf(fmaxf(v, 0.f));
        } else if (EPI == 5) {
            ((float*)C0)[(long)blockIdx.y * MROWS * ldc + (long)mm * ldc + nn] = v;
        } else {            // QKV head-split
            int which = nn >> 9, col = nn & 511;
            if (which == 0)      scat_sd((u16*)C0, mm, col, v);
            else if (which == 1) scat_sd((u16*)C1, mm, col, v);
            else                 scat_ds((u16*)C2, mm, col, v);
        }
    }
}

// ---------------------------------------------------------------------------
// Flash attention: block = (head = bid & 63, qt = bid >> 6) so all 8 q-tiles
// of a head land on ONE XCD. 4 waves x 16 q-rows. KV tiles of 128, double-
// buffered LDS, both-sides XOR swizzle on K and V. Online softmax in C-layout
// registers with T13 defer-max (skip rescale when max growth <= 8);
// P via swizzled per-wave LDS slab. setprio around MFMA.
// ---------------------------------------------------------------------------
template <bool CAUSAL>
__global__ __launch_bounds__(256) void flash_attn(const u16* __restrict__ qh, const u16* __restrict__ kh,
                                                  const u16* __restrict__ vT, u16* __restrict__ ctx)
{
    constexpr int KVB = 128;
    __shared__ __align__(16) u16 Kl[2][KVB * 64];    // kv x dh, swizzled
    __shared__ __align__(16) u16 Vl[2][64 * KVB];    // dh x kv, swizzled
    __shared__ __align__(16) u16 Pl[4][16 * KVB];    // per-wave P, swizzled
    const int lane = threadIdx.x & 63, wid = threadIdx.x >> 6;
    const int head = blockIdx.x & 63, qt = blockIdx.x >> 6;   // head-major: XCD = head%8
    const int q0 = qt * 64;
    const long hb = (long)head * HD;
    const int fr = lane & 15, fq = lane >> 4;
    const int swz = (fr & 7) << 4;

    bf16x8 qf[2];
    #pragma unroll
    for (int kf = 0; kf < 2; ++kf)
        qf[kf] = *(const bf16x8*)(qh + hb + (long)(q0 + wid * 16 + fr) * 64 + kf * 32 + fq * 8);

    const int nt = CAUSAL ? (q0 >> 7) + 1 : SEQ / KVB;

    auto stage = [&](int buf, int t) {
        const long kv0 = (long)t * KVB;
        const int kr = lane >> 3;                        // K: 8 rows/chunk
        const int kcol = ((lane & 7) ^ kr) * 8;
        for (int c = wid; c < 16; c += 4)
            gl_lds16(kh + hb + (kv0 + c * 8 + kr) * 64 + kcol, &Kl[buf][c * 512]);
        const int vr = lane >> 4;                        // V^T: 4 rows/chunk
        for (int c = wid; c < 16; c += 4) {
            int row = c * 4 + vr;
            int vcol = ((lane & 15) ^ (row & 7)) * 8;
            gl_lds16(vT + hb + (long)row * SEQ + kv0 + vcol, &Vl[buf][c * 512]);
        }
    };

    float m[4], l[4];
    #pragma unroll
    for (int r = 0; r < 4; ++r) { m[r] = -3.0e38f; l[r] = 0.f; }
    f32x4 ao[4] = {};

    stage(0, 0);
    __syncthreads();
    int cur = 0;
    for (int t = 0; t < nt; ++t) {
        if (t + 1 < nt) stage(cur ^ 1, t + 1);
        f32x4 as[8] = {};
        const char* kb = (const char*)&Kl[cur][0];
        __builtin_amdgcn_s_setprio(1);
        #pragma unroll
        for (int nf = 0; nf < 8; ++nf)
            #pragma unroll
            for (int kf = 0; kf < 2; ++kf) {
                bf16x8 kfr = *(const bf16x8*)(kb + (nf * 16 + fr) * 128 + ((kf * 64 + fq * 16) ^ swz));
                as[nf] = __builtin_amdgcn_mfma_f32_16x16x32_bf16(qf[kf], kfr, as[nf], 0, 0, 0);
            }
        __builtin_amdgcn_s_setprio(0);
        const int kv0 = t * KVB;
        const int qrow = q0 + wid * 16 + fq * 4;
        #pragma unroll
        for (int nf = 0; nf < 8; ++nf)
            #pragma unroll
            for (int rr = 0; rr < 4; ++rr) {
                float s = as[nf][rr] * 0.125f;
                if (CAUSAL && (kv0 + nf * 16 + fr > qrow + rr)) s = -3.0e38f;
                as[nf][rr] = s;
            }
        // ---- online softmax with T13 defer-max ----
        float mnew[4]; int need = 0;
        #pragma unroll
        for (int rr = 0; rr < 4; ++rr) {
            float mx = as[0][rr];
            #pragma unroll
            for (int nf = 1; nf < 8; ++nf) mx = fmaxf(mx, as[nf][rr]);
            #pragma unroll
            for (int o = 1; o < 16; o <<= 1) mx = fmaxf(mx, __shfl_xor(mx, o, 64));
            mnew[rr] = fmaxf(m[rr], mx);
            need |= (mx > m[rr] + 8.f) ? 1 : 0;
        }
        if (__any(need)) {                 // wave-uniform rescale branch
            #pragma unroll
            for (int rr = 0; rr < 4; ++rr) {
                float ps = __expf(m[rr] - mnew[rr]);
                m[rr] = mnew[rr];
                l[rr] *= ps;
                #pragma unroll
                for (int nf = 0; nf < 4; ++nf) ao[nf][rr] *= ps;
            }
        }
        float rsum[4] = {0.f, 0.f, 0.f, 0.f};
        u16* pw = &Pl[wid][0];
        #pragma unroll
        for (int nf = 0; nf < 8; ++nf)
            #pragma unroll
            for (int rr = 0; rr < 4; ++rr) {
                float p = __expf(as[nf][rr] - m[rr]);   // bounded by e^8 when deferred
                rsum[rr] += p;
                int row = fq * 4 + rr;
                int byte = (row * 256 + (nf * 16 + fr) * 2) ^ ((row & 7) << 4);
                *(u16*)((char*)pw + byte) = f2bf(p);
            }
        #pragma unroll
        for (int rr = 0; rr < 4; ++rr) {
            #pragma unroll
            for (int o = 1; o < 16; o <<= 1) rsum[rr] += __shfl_xor(rsum[rr], o, 64);
            l[rr] += rsum[rr];
        }
        const char* vb = (const char*)&Vl[cur][0];
        __builtin_amdgcn_s_setprio(1);
        #pragma unroll
        for (int kf = 0; kf < 4; ++kf) {
            int pbyte = (fr * 256 + kf * 64 + fq * 16) ^ swz;
            bf16x8 pa = *(const bf16x8*)((const char*)pw + pbyte);
            #pragma unroll
            for (int nf = 0; nf < 4; ++nf) {
                bf16x8 vf = *(const bf16x8*)(vb + (nf * 16 + fr) * 256 + ((kf * 64 + fq * 16) ^ swz));
                ao[nf] = __builtin_amdgcn_mfma_f32_16x16x32_bf16(pa, vf, ao[nf], 0, 0, 0);
            }
        }
        __builtin_amdgcn_s_setprio(0);
        __syncthreads();
        cur ^= 1;
    }
    const int b = head >> 3, h = head & 7;
    #pragma unroll
    for (int nf = 0; nf < 4; ++nf)
        #pragma unroll
        for (int rr = 0; rr < 4; ++rr) {
            int qq = q0 + wid * 16 + fq * 4 + rr;
            ctx[((long)(b * SEQ + qq)) * DIM + h * 64 + nf * 16 + fr] = f2bf(ao[nf][rr] / l[rr]);
        }
}

// ---------------------------------------------------------------------------
// xb = LayerNorm(xb + y) * g + be, in place (y bf16).
// ---------------------------------------------------------------------------
__global__ __launch_bounds__(256) void add_ln(u16* xb, const u16* __restrict__ y,
                                              const float* __restrict__ g, const float* __restrict__ be)
{
    int row = blockIdx.x * 4 + (threadIdx.x >> 6);
    int lane = threadIdx.x & 63;
    long off = (long)row * DIM + lane * 8;
    u16x8 xv = *(const u16x8*)(xb + off);
    u16x8 yv = *(const u16x8*)(y + off);
    float v[8];
    #pragma unroll
    for (int j = 0; j < 8; ++j) v[j] = bf2f(xv[j]) + bf2f(yv[j]);
    float sum = 0.f;
    #pragma unroll
    for (int j = 0; j < 8; ++j) sum += v[j];
    #pragma unroll
    for (int o = 32; o; o >>= 1) sum += __shfl_xor(sum, o, 64);
    float mean = sum * (1.0f / DIM);
    float vs = 0.f;
    #pragma unroll
    for (int j = 0; j < 8; ++j) { float d = v[j] - mean; vs += d * d; }
    #pragma unroll
    for (int o = 32; o; o >>= 1) vs += __shfl_xor(vs, o, 64);
    float rstd = rsqrtf(vs * (1.0f / DIM) + 1e-5f);
    u16x8 ob;
    #pragma unroll
    for (int j = 0; j < 8; ++j) {
        int col = lane * 8 + j;
        ob[j] = f2bf((v[j] - mean) * rstd * g[col] + be[col]);
    }
    *(u16x8*)(xb + off) = ob;
}

// ---------------------------------------------------------------------------
// xb = LayerNorm(xb + y0 + y1 + bias) * g + be  (split-K f32 partials reduce).
// If xf != nullptr, also write f32 copy (final output).
// ---------------------------------------------------------------------------
__global__ __launch_bounds__(256) void add_ln2(u16* xb, const float* __restrict__ yf,
                                               const float* __restrict__ bias,
                                               const float* __restrict__ g, const float* __restrict__ be,
                                               float* __restrict__ xf)
{
    int row = blockIdx.x * 4 + (threadIdx.x >> 6);
    int lane = threadIdx.x & 63;
    long off = (long)row * DIM + lane * 8;
    u16x8 xv = *(const u16x8*)(xb + off);
    float4 a0 = *(const float4*)(yf + off);
    float4 a1 = *(const float4*)(yf + off + 4);
    float4 b0 = *(const float4*)(yf + (long)MROWS * DIM + off);
    float4 b1 = *(const float4*)(yf + (long)MROWS * DIM + off + 4);
    float v[8] = { a0.x + b0.x, a0.y + b0.y, a0.z + b0.z, a0.w + b0.w,
                   a1.x + b1.x, a1.y + b1.y, a1.z + b1.z, a1.w + b1.w };
    #pragma unroll
    for (int j = 0; j < 8; ++j) v[j] += bf2f(xv[j]) + bias[lane * 8 + j];
    float sum = 0.f;
    #pragma unroll
    for (int j = 0; j < 8; ++j) sum += v[j];
    #pragma unroll
    for (int o = 32; o; o >>= 1) sum += __shfl_xor(sum, o, 64);
    float mean = sum * (1.0f / DIM);
    float vs = 0.f;
    #pragma unroll
    for (int j = 0; j < 8; ++j) { float d = v[j] - mean; vs += d * d; }
    #pragma unroll
    for (int o = 32; o; o >>= 1) vs += __shfl_xor(vs, o, 64);
    float rstd = rsqrtf(vs * (1.0f / DIM) + 1e-5f);
    float outv[8]; u16x8 ob;
    #pragma unroll
    for (int j = 0; j < 8; ++j) {
        int col = lane * 8 + j;
        float r = (v[j] - mean) * rstd * g[col] + be[col];
        outv[j] = r; ob[j] = f2bf(r);
    }
    *(u16x8*)(xb + off) = ob;
    if (xf) {
        *(float4*)(xf + off)     = *(const float4*)&outv[0];
        *(float4*)(xf + off + 4) = *(const float4*)&outv[4];
    }
}

// ---------------------------------------------------------------------------
extern "C" void kernel_launch(void* const* d_in, const int* in_sizes, int n_in,
                              void* d_out, int out_size, void* d_ws, size_t ws_size,
                              hipStream_t stream)
{
    const int*   targets = (const int*)  d_in[0];
    const float* memory  = (const float*)d_in[1];
    // d_in[2]=trg_mask (causal, analytic), d_in[3]=memory_mask (all false) -> unread
    const float* emb     = (const float*)d_in[4];
    const float* Wg[8]; for (int i = 0; i < 8; ++i) Wg[i] = (const float*)d_in[5 + i];
    const float* bg[8]; for (int i = 0; i < 8; ++i) bg[i] = (const float*)d_in[13 + i];
    const float* W1  = (const float*)d_in[21];
    const float* b1  = (const float*)d_in[22];
    const float* W2  = (const float*)d_in[23];
    const float* b2  = (const float*)d_in[24];
    const float* g1  = (const float*)d_in[25];
    const float* g2  = (const float*)d_in[26];
    const float* g3  = (const float*)d_in[27];
    const float* be1 = (const float*)d_in[28];
    const float* be2 = (const float*)d_in[29];
    const float* be3 = (const float*)d_in[30];

    char* w = (char*)d_ws;
    auto take = [&](size_t n) -> char* { char* p = w; w += (n + 255) & ~(size_t)255; return p; };
    u16*   wqkvT = (u16*)take((size_t)NLAY * 3 * SQ * 2);   // self  [L][1536][512]
    u16*   wcatT = (u16*)take((size_t)NLAY * 3 * SQ * 2);   // cross [L][1536][512]
    u16*   woT   = (u16*)take((size_t)NLAY * SQ * 2);
    u16*   wocT  = (u16*)take((size_t)NLAY * SQ * 2);
    u16*   w1T   = (u16*)take((size_t)NLAY * DIM * DFFN * 2);
    u16*   w2T   = (u16*)take((size_t)NLAY * DIM * DFFN * 2);
    float* bqkv  = (float*)take((size_t)NLAY * 3 * DIM * 4);
    float* bqkvc = (float*)take((size_t)NLAY * 3 * DIM * 4);
    u16*   xb    = (u16*)  take((size_t)MROWS * DIM * 2);   // bf16 residual stream
    u16*   y     = (u16*)  take((size_t)MROWS * DIM * 2);
    float* yf    = (float*)take((size_t)2 * MROWS * DIM * 4); // split-K f32 partials
    u16*   memb  = (u16*)  take((size_t)MROWS * DIM * 2);
    u16*   qh    = (u16*)  take((size_t)MROWS * DIM * 2);
    u16*   kh    = (u16*)  take((size_t)MROWS * DIM * 2);
    u16*   vT    = (u16*)  take((size_t)MROWS * DIM * 2);
    u16*   ctx   = (u16*)  take((size_t)MROWS * DIM * 2);
    u16*   h1    = (u16*)  take((size_t)MROWS * DFFN * 2);

    TP tp;
    tp.in[0] = Wg[0]; tp.out[0] = wqkvT;          tp.ls[0] = 3 * SQ;
    tp.in[1] = Wg[1]; tp.out[1] = wqkvT + SQ;     tp.ls[1] = 3 * SQ;
    tp.in[2] = Wg[2]; tp.out[2] = wqkvT + 2 * SQ; tp.ls[2] = 3 * SQ;
    tp.in[3] = Wg[3]; tp.out[3] = woT;            tp.ls[3] = SQ;
    tp.in[4] = Wg[4]; tp.out[4] = wcatT;          tp.ls[4] = 3 * SQ;
    tp.in[5] = Wg[5]; tp.out[5] = wcatT + SQ;     tp.ls[5] = 3 * SQ;
    tp.in[6] = Wg[6]; tp.out[6] = wcatT + 2 * SQ; tp.ls[6] = 3 * SQ;
    tp.in[7] = Wg[7]; tp.out[7] = wocT;           tp.ls[7] = SQ;
    transpose8<<<dim3(16, 16, 8 * NLAY), 256, 0, stream>>>(tp);
    transpose_w12<<<dim3(64, 16, 2 * NLAY), 256, 0, stream>>>(W1, W2, w1T, w2T);
    CB cb; cb.s[0] = bg[0]; cb.s[1] = bg[1]; cb.s[2] = bg[2];
    cb.s[3] = bg[4]; cb.s[4] = bg[5]; cb.s[5] = bg[6];
    concat2<<<2 * NLAY * 3 * DIM / 256, 256, 0, stream>>>(cb, bqkv, bqkvc);
    prep_act<<<4096, 256, 0, stream>>>(targets, emb, xb, memory, memb);

    const int BIG = 1 << 30;
    for (int i = 0; i < NLAY; ++i) {
        const u16 *wqkv = wqkvT + (long)i * 3 * SQ, *wcat = wcatT + (long)i * 3 * SQ;
        const u16 *wo = woT + (long)i * SQ, *woc = wocT + (long)i * SQ;
        const u16 *w1t = w1T + (long)i * DIM * DFFN, *w2t = w2T + (long)i * DIM * DFFN;
        const float *bo = bg[3] + i * DIM, *boc = bg[7] + i * DIM;

        // ---- self attention (causal) ----
        gemm_t<128, 128, 64, 4><<<384, 256, 0, stream>>>(xb, xb, wqkv, qh, kh, vT, bqkv + i * 3 * DIM, DIM, DIM, 0, 12, BIG);
        flash_attn<true><<<BATCH * NHEAD * (SEQ / 64), 256, 0, stream>>>(qh, kh, vT, ctx);
        gemm_t<64, 64, 128, 0><<<512, 256, 0, stream>>>(ctx, ctx, wo, y, nullptr, nullptr, bo, DIM, DIM, DIM, 8, BIG);
        add_ln<<<MROWS / 4, 256, 0, stream>>>(xb, y, g1 + i * DIM, be1 + i * DIM);

        // ---- cross attention (no mask): fused Q(from xb) | K,V (from memb) ----
        gemm_t<128, 128, 64, 4><<<384, 256, 0, stream>>>(xb, memb, wcat, qh, kh, vT, bqkvc + i * 3 * DIM, DIM, DIM, 0, 12, 512);
        flash_attn<false><<<BATCH * NHEAD * (SEQ / 64), 256, 0, stream>>>(qh, kh, vT, ctx);
        gemm_t<64, 64, 128, 0><<<512, 256, 0, stream>>>(ctx, ctx, woc, y, nullptr, nullptr, boc, DIM, DIM, DIM, 8, BIG);
        add_ln<<<MROWS / 4, 256, 0, stream>>>(xb, y, g2 + i * DIM, be2 + i * DIM);

        // ---- FFN ----
        gemm_t<128, 128, 64, 1><<<512, 256, 0, stream>>>(xb, xb, w1t, h1, nullptr, nullptr, b1 + i * DFFN, DIM, DIM, DFFN, 16, BIG);
        // FFN2 split-K=2: grid (512, 2); f32 partials into yf; bias+reduce fused in add_ln2
        gemm_t<64, 64, 128, 5><<<dim3(512, 2), 256, 0, stream>>>(h1, h1, w2t, yf, nullptr, nullptr, nullptr,
                                                                 DFFN / 2, DFFN, DIM, 8, BIG);
        add_ln2<<<MROWS / 4, 256, 0, stream>>>(xb, yf, b2 + i * DIM, g3 + i * DIM, be3 + i * DIM,
                                               (i == NLAY - 1) ? (float*)d_out : nullptr);
    }
}